// Round 14
// baseline (38.505 us; speedup 1.0000x reference)
//
#include <hip/hip_runtime.h>
#include <math.h>
#include <stdint.h>

// Problem dims (fixed by reference setup_inputs)
#define BB 4
#define CC 8
#define PP 20
#define AA 30
#define SS 4
#define TT 2048
#define NB 18

#define TC 128                  // t-chunk (K-slab) per iteration
#define NCH (TT / TC)           // 16 chunks
#define PG 2                    // p's per block (both handled by EVERY wave)
#define NPG (PP / PG)           // 10 p-groups
#define WSTR 132                // f16 row stride: 264 B -> 2-row bank step 2 (2-way free)
#define WROWS 19                // rows 0..17 = W, row 18 = dump row for the unwrapped edge
#define NTH 256                 // 4 waves = 4 K-quarters; each does both p's

// Relaxed barrier (epilogue only): LDS-visibility, globals stay in flight.
#define BAR() do { asm volatile("s_waitcnt lgkmcnt(0)" ::: "memory"); \
                   __builtin_amdgcn_s_barrier(); } while (0)

typedef _Float16 half4_t __attribute__((ext_vector_type(4)));
typedef _Float16 half8_t __attribute__((ext_vector_type(8)));
typedef float f32x16 __attribute__((ext_vector_type(16)));

__device__ __forceinline__ void weight_top2(float x, int& n0, int& n1,
                                            float& w0, float& w1)
{
    const float PI_F  = 3.14159265358979323846f;
    const float INV_H = 2.8647913f;           // 18 / (2*pi)
    float u = (x + PI_F) * INV_H;             // in [0, 18]
    n0 = (int)floorf(u);
    n0 = n0 < 0 ? 0 : (n0 > NB - 1 ? NB - 1 : n0);
    float f  = u - (float)n0 - 0.5f;          // [-0.5, 0.5]
    float af = fabsf(f);
    n1 = n0 + (f >= 0.0f ? 1 : -1);
    float e;
    if (n1 < 0) {                             // reference's unwrapped low edge: w1 ~ 7e-16
        e = 0.0f; n1 = NB;                    // row 18 (never extracted)
    } else {
        if (n1 == NB) n1 = 0;                 // positive wrap: same gap formula
        // exp(-(H*(1-2af))*100) = exp(69.81317*af - 34.906585), folded
        e = __expf(fmaf(af, 69.81317008f, -34.90658504f));
    }
    w0 = __builtin_amdgcn_rcpf(1.0f + e);     // rel err ~1e-7 << f16 quantization
    w1 = 1.0f - w0;
}

// ---------------------------------------------------------------------------
// BARRIER-FREE main loop, LDS-staged (fixes r12's gather mistake).
// Block = (bc, s, pg); wave kh owns t-cols [kh*32, kh*32+32) of EVERYTHING:
// W scatter/unwrite/A-reads, ampT staging writes AND B-reads all live in the
// wave's own column stripe -> every LDS dependence is wave-internal, ordered
// by the per-wave in-order LDS pipe + compiler lgkmcnt. No __syncthreads in
// the main loop at all; waves free-run across all 16 chunks so their
// latency windows decorrelate (the r7-r13 lockstep is gone).
// Single-buffered ampT (program order: reads of chunk c precede writes of
// c+1). 18.4 KB LDS; grid 1280 = exactly 5 blocks/CU, 20 waves/CU.
// XCD swizzle (verified r12: FETCH 25.6 MB): amp-slice sharers on one XCD.
// Epilogue: BAR -> dump partials over the dead arena -> BAR -> merge.
// ---------------------------------------------------------------------------
__global__ __launch_bounds__(NTH, 5)
void mi_fused_kernel(const float* __restrict__ phase,
                     const float* __restrict__ amp,
                     float* __restrict__ out)
{
    // Arena: [Wl0 | Wl1 | ampT] = 17,952 B live in main loop;
    // epilogue overlays df[8*576] f32 = 18,432 B (after BAR).
    __shared__ __align__(16) char arena[18496];
    _Float16* const Wl0  = (_Float16*)arena;
    _Float16* const Wl1  = Wl0 + WROWS * WSTR;
    _Float16* const ampT = Wl1 + WROWS * WSTR;   // [30][WSTR], wave-striped cols
    float* const df = (float*)arena;

    const int tid = threadIdx.x;
    // ---- XCD-aware swizzle (bijective 1280->1280): sharers of one amp slice
    //      land on one XCD (physical XCD ~ blockIdx%8 round-robin dispatch)
    const int bid = blockIdx.x;
    const int x   = bid & 7;                   // physical XCD
    const int kk  = bid >> 3;                  // 0..159
    const int pg  = kk % NPG;                  // member within amp-sharing group
    const int g   = x + 8 * (kk / NPG);        // 0..127 = bc*SS + s
    const int s   = g & (SS - 1);
    const int bc  = g >> 2;                    // b*CC + c

    const int kh   = tid >> 6;                 // wave = K-quarter (0..3)
    const int lane = tid & 63;
    const int mrow = lane & 31;
    const int mlh  = lane >> 5;
    const int arow = mrow < WROWS ? mrow : (WROWS - 1);  // A rows >=19 -> row 18 (bcast)
    const int brow = mrow < AA    ? mrow : (AA - 1);     // B rows 30,31 -> dup (unused)
    const int col  = kh * 32 + mrow;           // scatter: this lane's owned t-column
    _Float16* const ptile = mlh ? Wl1 : Wl0;   // scatter: this lane's owned p tile

    const float* am  = amp + (size_t)bc * (AA * SS * TT) + (size_t)s * TT;
    // per-lane phase pointer: p = pg*PG + mlh, t-offset = col
    const float* phl = phase + ((size_t)(bc * PP + pg * PG + mlh) * SS + s) * TT + col;

    // wave-striped staging lanes: row sa (+16 on pass B), 8-float segment so
    const int sa  = lane >> 2;                 // 0..15
    const int so  = lane & 3;                  // segment: floats so*8 .. so*8+7
    const int saB = 16 + sa;                   // pass-B row (active < 30)
    const int saBc = saB < AA ? saB : (AA - 1);            // clamped load row
    const float* amA = am + (size_t)sa  * (SS * TT) + kh * 32 + so * 8;
    const float* amB = am + (size_t)saBc * (SS * TT) + kh * 32 + so * 8;
    _Float16* const stA = &ampT[sa  * WSTR + kh * 32 + so * 8];
    _Float16* const stB = &ampT[saB * WSTR + kh * 32 + so * 8];

    // ---- prologue (all wave-local, NO barrier): zero own W cols,
    //      stage chunk 0 stripe, load chunk-0 phase ----
    #pragma unroll
    for (int r = 0; r < WROWS; ++r)
        ptile[r * WSTR + col] = (_Float16)0.0f;
    {
        float4 u0 = *(const float4*)(amA);
        float4 u1 = *(const float4*)(amA + 4);
        half8_t h0 = { (_Float16)u0.x, (_Float16)u0.y, (_Float16)u0.z, (_Float16)u0.w,
                       (_Float16)u1.x, (_Float16)u1.y, (_Float16)u1.z, (_Float16)u1.w };
        *(half8_t*)stA = h0;
        if (saB < AA) {
            float4 v0 = *(const float4*)(amB);
            float4 v1 = *(const float4*)(amB + 4);
            half8_t h1 = { (_Float16)v0.x, (_Float16)v0.y, (_Float16)v0.z, (_Float16)v0.w,
                           (_Float16)v1.x, (_Float16)v1.y, (_Float16)v1.z, (_Float16)v1.w };
            *(half8_t*)stB = h1;
        }
    }
    float phv = phl[0];

    f32x16 acc0 = {}, acc1 = {};               // p0 / p1 accumulators
    int pn0 = 0, pn1 = 0;

    #pragma unroll 1
    for (int c = 0; c < NCH; ++c) {
        // ---- issue next-chunk global loads EARLY (consumed after MFMA) ----
        float nphv = 0.0f;
        float4 sA0, sA1, sB0, sB1;
        if (c + 1 < NCH) {
            nphv = phl[(c + 1) * TC];
            const float* pa = amA + (c + 1) * TC;
            const float* pb = amB + (c + 1) * TC;
            sA0 = *(const float4*)(pa);
            sA1 = *(const float4*)(pa + 4);
            sB0 = *(const float4*)(pb);
            sB1 = *(const float4*)(pb + 4);
        }

        // ---- unwrite previous chunk's entries, scatter this chunk's ----
        if (c > 0) {
            ptile[pn0 * WSTR + col] = (_Float16)0.0f;
            ptile[pn1 * WSTR + col] = (_Float16)0.0f;
        }
        {
            int n0, n1; float w0, w1;
            weight_top2(phv, n0, n1, w0, w1);
            ptile[n0 * WSTR + col] = (_Float16)w0;
            ptile[n1 * WSTR + col] = (_Float16)w1;
            pn0 = n0; pn1 = n1;
        }

        // ---- 2 K-steps x 2 p: 1 B-frag read feeds both MFMAs ----
        __builtin_amdgcn_s_setprio(1);
        #pragma unroll
        for (int ks = 0; ks < 2; ++ks) {
            int t0 = kh * 32 + ks * 16 + mlh * 8;
            const _Float16* Bb  = ampT + brow * WSTR + t0;
            const _Float16* A0b = Wl0  + arow * WSTR + t0;
            const _Float16* A1b = Wl1  + arow * WSTR + t0;
            half4_t b0 = *(const half4_t*)Bb;
            half4_t b1 = *(const half4_t*)(Bb + 4);
            half4_t p0a = *(const half4_t*)A0b;
            half4_t p0b = *(const half4_t*)(A0b + 4);
            half4_t p1a = *(const half4_t*)A1b;
            half4_t p1b = *(const half4_t*)(A1b + 4);
            half8_t bv  = __builtin_shufflevector(b0, b1, 0, 1, 2, 3, 4, 5, 6, 7);
            half8_t a0v = __builtin_shufflevector(p0a, p0b, 0, 1, 2, 3, 4, 5, 6, 7);
            half8_t a1v = __builtin_shufflevector(p1a, p1b, 0, 1, 2, 3, 4, 5, 6, 7);
            acc0 = __builtin_amdgcn_mfma_f32_32x32x16_f16(a0v, bv, acc0, 0, 0, 0);
            acc1 = __builtin_amdgcn_mfma_f32_32x32x16_f16(a1v, bv, acc1, 0, 0, 0);
        }
        __builtin_amdgcn_s_setprio(0);

        // ---- write-late: stage next chunk into own stripe (single buffer:
        //      per-wave in-order LDS puts these after this chunk's reads) ----
        if (c + 1 < NCH) {
            half8_t h0 = { (_Float16)sA0.x, (_Float16)sA0.y, (_Float16)sA0.z, (_Float16)sA0.w,
                           (_Float16)sA1.x, (_Float16)sA1.y, (_Float16)sA1.z, (_Float16)sA1.w };
            *(half8_t*)stA = h0;
            if (saB < AA) {
                half8_t h1 = { (_Float16)sB0.x, (_Float16)sB0.y, (_Float16)sB0.z, (_Float16)sB0.w,
                               (_Float16)sB1.x, (_Float16)sB1.y, (_Float16)sB1.z, (_Float16)sB1.w };
                *(half8_t*)stB = h1;
            }
        }
        phv = nphv;
    }

    // ---- epilogue: BAR (all waves done with W/ampT) -> dump -> BAR -> merge
    BAR();
    #pragma unroll
    for (int r = 0; r < 16; ++r) {
        int row = (r & 3) + 8 * (r >> 2) + 4 * mlh;   // HW-verified C/D layout
        if (row < NB) {
            df[(kh * 2 + 0) * 576 + row * 32 + mrow] = acc0[r];
            df[(kh * 2 + 1) * 576 + row * 32 + mrow] = acc1[r];
        }
    }
    BAR();

    // waves 0,1: reduce 4 kh-partials for p = pg*PG + kh, entropy, store
    if (kh < PG && lane < AA) {
        float v[NB], tot = 0.0f;
        #pragma unroll
        for (int n = 0; n < NB; ++n) {
            v[n] = df[(0 * 2 + kh) * 576 + n * 32 + lane]
                 + df[(1 * 2 + kh) * 576 + n * 32 + lane]
                 + df[(2 * 2 + kh) * 576 + n * 32 + lane]
                 + df[(3 * 2 + kh) * 576 + n * 32 + lane];
            tot += v[n];
        }
        float inv = 1.0f / (tot + 1e-10f);
        float ne = 0.0f;
        #pragma unroll
        for (int n = 0; n < NB; ++n) {
            float pv = fmaxf(v[n] * inv, 1e-10f);
            ne += pv * logf(pv);
        }
        out[((size_t)(bc * SS + s) * PP + pg * PG + kh) * AA + lane] =
            1.0f + ne * 0.345975362f;          // 1/log(18)
    }
}

extern "C" void kernel_launch(void* const* d_in, const int* in_sizes, int n_in,
                              void* d_out, int out_size, void* d_ws, size_t ws_size,
                              hipStream_t stream)
{
    const float* phase = (const float*)d_in[0];
    const float* amp   = (const float*)d_in[1];
    float* out = (float*)d_out;
    hipLaunchKernelGGL(mi_fused_kernel, dim3(BB * CC * SS * NPG), dim3(NTH),
                       0, stream, phase, amp, out);
}

// Round 15
// 28.129 us; speedup vs baseline: 1.3689x; 1.3689x over previous
//
#include <hip/hip_runtime.h>
#include <math.h>
#include <stdint.h>

// Problem dims (fixed by reference setup_inputs)
#define BB 4
#define CC 8
#define PP 20
#define AA 30
#define SS 4
#define TT 2048
#define NB 18

#define TC 128                  // t-chunk (K-slab) per iteration
#define NCH (TT / TC)           // 16 chunks
#define PG 2                    // p's per block (both handled by EVERY wave)
#define NPG (PP / PG)           // 10 p-groups
#define WSTR 132                // f16 row stride: 264 B -> b64 pairs bank-step 2 (2-way free)
#define WROWS 19                // rows 0..17 = W, row 18 = dump row for the unwrapped edge
#define NTH 256                 // 4 waves = 4 K-quarters; each does both p's (B-frag reuse)

// Relaxed barrier: LDS-visibility only; global loads stay in flight across it.
#define BAR() do { asm volatile("s_waitcnt lgkmcnt(0)" ::: "memory"); \
                   __builtin_amdgcn_s_barrier(); } while (0)

typedef _Float16 half4_t __attribute__((ext_vector_type(4)));
typedef _Float16 half8_t __attribute__((ext_vector_type(8)));
typedef float f32x16 __attribute__((ext_vector_type(16)));

__device__ __forceinline__ void weight_top2(float x, int& n0, int& n1,
                                            float& w0, float& w1)
{
    const float PI_F  = 3.14159265358979323846f;
    const float INV_H = 2.8647913f;           // 18 / (2*pi)
    float u = (x + PI_F) * INV_H;             // in [0, 18]
    n0 = (int)floorf(u);
    n0 = n0 < 0 ? 0 : (n0 > NB - 1 ? NB - 1 : n0);
    float f  = u - (float)n0 - 0.5f;          // [-0.5, 0.5]
    float af = fabsf(f);
    n1 = n0 + (f >= 0.0f ? 1 : -1);
    float e;
    if (n1 < 0) {                             // reference's unwrapped low edge: w1 ~ 7e-16
        e = 0.0f; n1 = NB;                    // row 18 gets garbage (never extracted)
    } else {
        if (n1 == NB) n1 = 0;                 // positive wrap: same gap formula
        // exp(-(H*(1-2af))*100) = exp(69.81317*af - 34.906585), folded
        e = __expf(fmaf(af, 69.81317008f, -34.90658504f));
    }
    w0 = __builtin_amdgcn_rcpf(1.0f + e);     // rel err ~1e-7 << f16 quantization
    w1 = 1.0f - w0;
}

// ---------------------------------------------------------------------------
// r11 restored — the measured optimum of this structure family (28.3 us).
// Block = (bc, s, pg); wave kh owns t-columns [kh*32, kh*32+32) of each chunk
// and computes BOTH p tiles over that K-range: per K-step it reads ONE
// B-fragment and TWO A-fragments (B-frag reuse), issuing 2 MFMAs.
// Scatter/unwrite: lane = (pi=lane>>5, cc=lane&31) -> own column of own tile,
// strictly wave-local. ampT double-buffer is the only cross-wave state ->
// ONE relaxed barrier per chunk (dbuf lets staging writes overlap reads —
// r14 proved removing it serializes on aliasing). 25.9 KB LDS, grid 1280 =
// exactly 5 blocks/CU, 20 waves/CU.
// XCD swizzle (verified r12: FETCH 25.6 MB): amp-slice sharers on one XCD.
// Refuted levers (kept out): rotation (r13 -13%), barrier-free (r14 -26%),
// 2-deep staging (r8 -7%), direct-gather B (r12 -49%).
// ---------------------------------------------------------------------------
__global__ __launch_bounds__(NTH, 5)
void mi_fused_kernel(const float* __restrict__ phase,
                     const float* __restrict__ amp,
                     float* __restrict__ out)
{
    // One arena: [Wl0 | Wl1 | ampT0 | ampT1] = 25,872 B (epilogue dump overlays)
    __shared__ __align__(16) _Float16 lds[2 * WROWS * WSTR + 2 * AA * WSTR];
    _Float16* const Wl0 = lds;
    _Float16* const Wl1 = lds + WROWS * WSTR;
    _Float16* const amp0 = lds + 2 * WROWS * WSTR;

    const int tid = threadIdx.x;
    // ---- XCD-aware swizzle (bijective 1280->1280): sharers of one amp slice
    //      land on one XCD (physical XCD ~ blockIdx%8 round-robin dispatch)
    const int bid = blockIdx.x;
    const int x   = bid & 7;                   // physical XCD
    const int kk  = bid >> 3;                  // 0..159
    const int pg  = kk % NPG;                  // member within amp-sharing group
    const int g   = x + 8 * (kk / NPG);        // 0..127 = bc*SS + s
    const int s   = g & (SS - 1);
    const int bc  = g >> 2;                    // b*CC + c

    const int kh   = tid >> 6;                 // wave = K-quarter (0..3)
    const int lane = tid & 63;
    const int mrow = lane & 31;
    const int mlh  = lane >> 5;
    const int arow = mrow < WROWS ? mrow : (WROWS - 1);  // A rows >=19 -> row 18 (bcast)
    const int brow = mrow < AA    ? mrow : (AA - 1);     // B rows 30,31 -> dup (unused)
    const int col  = kh * 32 + mrow;           // scatter: this lane's owned t-column
    _Float16* const ptile = mlh ? Wl1 : Wl0;   // scatter: this lane's owned p tile

    const float* am  = amp + (size_t)bc * (AA * SS * TT) + (size_t)s * TT;
    // per-lane phase pointer: p = pg*PG + mlh, t-offset = col
    const float* phl = phase + ((size_t)(bc * PP + pg * PG + mlh) * SS + s) * TT + col;

    // ---- prologue: zero both W tiles, stage chunk 0, load phase col ----
    for (int i = tid; i < 627; i += NTH)       // 10,032 B = 627 uint4
        ((uint4*)lds)[i] = make_uint4(0u, 0u, 0u, 0u);
    #pragma unroll
    for (int j = 0; j < 4; ++j) {              // stage chunk 0: 960 quads, coop
        int q = tid + j * NTH;
        int a = q >> 5, tq = q & 31;           // 32 quads per row (TC/4)
        if (a < AA) {
            const float4 v = *(const float4*)&am[(size_t)a * (SS * TT) + tq * 4];
            half4_t h = { (_Float16)v.x, (_Float16)v.y, (_Float16)v.z, (_Float16)v.w };
            *(half4_t*)&amp0[a * WSTR + tq * 4] = h;
        }
    }
    float phv = phl[0];
    BAR();

    f32x16 acc0 = {}, acc1 = {};               // p0 / p1 accumulators
    int pn0 = 0, pn1 = 0;

    for (int c = 0; c < NCH; ++c) {
        const int cb = c & 1, tb = cb ^ 1;
        const _Float16* aB = amp0 + cb * (AA * WSTR);
        _Float16* aW = amp0 + tb * (AA * WSTR);

        // ---- issue next-chunk global loads EARLY (consumed after MFMA) ----
        float nphv = 0.0f;
        float4 stg[4];
        if (c + 1 < NCH) {
            nphv = phl[(c + 1) * TC];
            #pragma unroll
            for (int j = 0; j < 4; ++j) {
                int q = tid + j * NTH;
                int a = q >> 5, tq = q & 31;
                int ac = a < AA ? a : (AA - 1);          // clamp: no OOB read
                stg[j] = *(const float4*)&am[(size_t)ac * (SS * TT) + (c + 1) * TC + tq * 4];
            }
        }

        // ---- unwrite previous chunk's entries, scatter this chunk's ----
        if (c > 0) {
            ptile[pn0 * WSTR + col] = (_Float16)0.0f;
            ptile[pn1 * WSTR + col] = (_Float16)0.0f;
        }
        {
            int n0, n1; float w0, w1;
            weight_top2(phv, n0, n1, w0, w1);
            ptile[n0 * WSTR + col] = (_Float16)w0;
            ptile[n1 * WSTR + col] = (_Float16)w1;
            pn0 = n0; pn1 = n1;
        }

        // ---- 2 K-steps x 2 p: ONE B-frag read feeds both MFMAs ----
        __builtin_amdgcn_s_setprio(1);         // prefer MFMA-phase waves on SIMD
        #pragma unroll
        for (int ks = 0; ks < 2; ++ks) {
            int t0 = kh * 32 + ks * 16 + mlh * 8;
            const _Float16* Bb  = aB  + brow * WSTR + t0;
            const _Float16* A0b = Wl0 + arow * WSTR + t0;
            const _Float16* A1b = Wl1 + arow * WSTR + t0;
            half4_t b0 = *(const half4_t*)Bb;
            half4_t b1 = *(const half4_t*)(Bb + 4);
            half4_t p0a = *(const half4_t*)A0b;
            half4_t p0b = *(const half4_t*)(A0b + 4);
            half4_t p1a = *(const half4_t*)A1b;
            half4_t p1b = *(const half4_t*)(A1b + 4);
            half8_t bv  = __builtin_shufflevector(b0, b1, 0, 1, 2, 3, 4, 5, 6, 7);
            half8_t a0v = __builtin_shufflevector(p0a, p0b, 0, 1, 2, 3, 4, 5, 6, 7);
            half8_t a1v = __builtin_shufflevector(p1a, p1b, 0, 1, 2, 3, 4, 5, 6, 7);
            acc0 = __builtin_amdgcn_mfma_f32_32x32x16_f16(a0v, bv, acc0, 0, 0, 0);
            acc1 = __builtin_amdgcn_mfma_f32_32x32x16_f16(a1v, bv, acc1, 0, 0, 0);
        }
        __builtin_amdgcn_s_setprio(0);

        // ---- write-late: stage next chunk into the other buffer ----
        if (c + 1 < NCH) {
            #pragma unroll
            for (int j = 0; j < 4; ++j) {
                int q = tid + j * NTH;
                int a = q >> 5, tq = q & 31;
                if (a < AA) {
                    half4_t h = { (_Float16)stg[j].x, (_Float16)stg[j].y,
                                  (_Float16)stg[j].z, (_Float16)stg[j].w };
                    *(half4_t*)&aW[a * WSTR + tq * 4] = h;
                }
            }
        }
        phv = nphv;
        BAR();   // syncs ampT only: my reads of [cb] done; my writes to [tb] visible
    }
    // loop's final BAR: all MFMA reads of W/ampT complete -> arena reusable

    // ---- epilogue: dump [kh][pi][18][32] f32 partials over the arena ----
    float* const df = (float*)lds;             // 8 x 576 f32 = 18,432 B < 25,872 B
    #pragma unroll
    for (int r = 0; r < 16; ++r) {
        int row = (r & 3) + 8 * (r >> 2) + 4 * mlh;   // HW-verified C/D layout
        if (row < NB) {
            df[(kh * 2 + 0) * 576 + row * 32 + mrow] = acc0[r];
            df[(kh * 2 + 1) * 576 + row * 32 + mrow] = acc1[r];
        }
    }
    BAR();

    // waves 0,1: reduce 4 kh-partials for p = pg*PG + kh, entropy, store
    if (kh < PG && lane < AA) {
        float v[NB], tot = 0.0f;
        #pragma unroll
        for (int n = 0; n < NB; ++n) {
            v[n] = df[(0 * 2 + kh) * 576 + n * 32 + lane]
                 + df[(1 * 2 + kh) * 576 + n * 32 + lane]
                 + df[(2 * 2 + kh) * 576 + n * 32 + lane]
                 + df[(3 * 2 + kh) * 576 + n * 32 + lane];
            tot += v[n];
        }
        float inv = 1.0f / (tot + 1e-10f);
        float ne = 0.0f;
        #pragma unroll
        for (int n = 0; n < NB; ++n) {
            float pv = fmaxf(v[n] * inv, 1e-10f);
            ne += pv * logf(pv);
        }
        out[((size_t)(bc * SS + s) * PP + pg * PG + kh) * AA + lane] =
            1.0f + ne * 0.345975362f;          // 1/log(18)
    }
}

extern "C" void kernel_launch(void* const* d_in, const int* in_sizes, int n_in,
                              void* d_out, int out_size, void* d_ws, size_t ws_size,
                              hipStream_t stream)
{
    const float* phase = (const float*)d_in[0];
    const float* amp   = (const float*)d_in[1];
    float* out = (float*)d_out;
    hipLaunchKernelGGL(mi_fused_kernel, dim3(BB * CC * SS * NPG), dim3(NTH),
                       0, stream, phase, amp, out);
}